// Round 2
// baseline (7608.283 us; speedup 1.0000x reference)
//
#include <hip/hip_runtime.h>
#include <cmath>

#define CH_H   512
#define CH_IN  256
#define CH_OUT 256
#define TCH    128   // column chunk for the W1/prop pipeline

__device__ __forceinline__ float silu_f(float v) { return v / (1.0f + __expf(-v)); }

// ---------------- small edge/node kernels ----------------

__global__ void deg_kernel(const int* __restrict__ row, float* __restrict__ deg, int E) {
    int e = blockIdx.x * blockDim.x + threadIdx.x;
    if (e < E) atomicAdd(&deg[row[e]], 1.0f);
}

__global__ void dinv_kernel(const float* __restrict__ deg, float* __restrict__ dinv, int n) {
    int i = blockIdx.x * blockDim.x + threadIdx.x;
    if (i < n) {
        float d = deg[i];
        dinv[i] = d > 0.0f ? rsqrtf(fmaxf(d, 1e-12f)) : 0.0f;
    }
}

__global__ void norm_kernel(const int* __restrict__ row, const int* __restrict__ col,
                            const float* __restrict__ dinv, float* __restrict__ nrm, int E) {
    int e = blockIdx.x * blockDim.x + threadIdx.x;
    if (e < E) nrm[e] = -dinv[row[e]] * dinv[col[e]];
}

// ---------------- prop chunk: U[col, coff:coff+128] += nrm * T[row, 0:128] ----------------
// 256 threads/block = 8 edges/block, 32 threads (= 32 float4) per edge.

__global__ __launch_bounds__(256) void prop_chunk_kernel(
    const int* __restrict__ row, const int* __restrict__ col,
    const float* __restrict__ nrm, const float* __restrict__ T,
    float* __restrict__ U, int E, int coff)
{
    int t = threadIdx.x;
    int e = blockIdx.x * 8 + (t >> 5);
    if (e >= E) return;
    int q = t & 31;
    int r = row[e], c = col[e];
    float w = nrm[e];
    const float4 tv = *(const float4*)(T + (size_t)r * TCH + q * 4);
    float* up = U + (size_t)c * CH_H + coff + q * 4;
    atomicAdd(up + 0, w * tv.x);
    atomicAdd(up + 1, w * tv.y);
    atomicAdd(up + 2, w * tv.z);
    atomicAdd(up + 3, w * tv.w);
}

// ---------------- fp32 tiled GEMM with fused epilogue ----------------
// Cout[M,Nn] = op( (ACCUM? Cin : 0) + A[M,K] @ B[K,Nn] + (BIAS? bias : 0) )
// Strides lda/ldb/ldc allow column-sliced B and narrow C. K%16==0, Nn%64==0.
// In-place (Cin == Cout) is safe: each element read once / written once by
// the same thread.

template<int ACCUM, int BIAS, int SILU>
__global__ __launch_bounds__(256) void gemm_kernel(
    const float* __restrict__ A, int lda,
    const float* __restrict__ B, int ldb,
    const float* __restrict__ Cin, float* __restrict__ Cout, int ldc,
    const float* __restrict__ bias, int M, int Nn, int K)
{
    __shared__ float As[16][64];   // [k][row]
    __shared__ float Bs[16][64];   // [k][col]

    const int t  = threadIdx.x;
    const int m0 = blockIdx.y * 64;
    const int n0 = blockIdx.x * 64;

    const int la_r = t >> 2;          // 0..63 row within tile
    const int la_k = (t & 3) * 4;     // 0,4,8,12
    const int lb_k = t >> 4;          // 0..15
    const int lb_n = (t & 15) * 4;    // 0..60

    const int ty = t >> 4;            // rows ty*4..ty*4+3
    const int tx = t & 15;            // cols tx*4..tx*4+3

    float acc[4][4] = {};

    for (int k0 = 0; k0 < K; k0 += 16) {
        float4 av;
        const int ar = m0 + la_r;
        if (ar < M) av = *(const float4*)(A + (size_t)ar * lda + k0 + la_k);
        else        av = make_float4(0.f, 0.f, 0.f, 0.f);
        As[la_k + 0][la_r] = av.x;
        As[la_k + 1][la_r] = av.y;
        As[la_k + 2][la_r] = av.z;
        As[la_k + 3][la_r] = av.w;

        const float4 bv = *(const float4*)(B + (size_t)(k0 + lb_k) * ldb + n0 + lb_n);
        *(float4*)&Bs[lb_k][lb_n] = bv;

        __syncthreads();

        #pragma unroll
        for (int k = 0; k < 16; ++k) {
            const float4 a = *(const float4*)&As[k][ty * 4];
            const float4 b = *(const float4*)&Bs[k][tx * 4];
            acc[0][0] += a.x * b.x; acc[0][1] += a.x * b.y; acc[0][2] += a.x * b.z; acc[0][3] += a.x * b.w;
            acc[1][0] += a.y * b.x; acc[1][1] += a.y * b.y; acc[1][2] += a.y * b.z; acc[1][3] += a.y * b.w;
            acc[2][0] += a.z * b.x; acc[2][1] += a.z * b.y; acc[2][2] += a.z * b.z; acc[2][3] += a.z * b.w;
            acc[3][0] += a.w * b.x; acc[3][1] += a.w * b.y; acc[3][2] += a.w * b.z; acc[3][3] += a.w * b.w;
        }
        __syncthreads();
    }

    float4 bb = make_float4(0.f, 0.f, 0.f, 0.f);
    if (BIAS) bb = *(const float4*)(bias + n0 + tx * 4);

    #pragma unroll
    for (int i = 0; i < 4; ++i) {
        const int r = m0 + ty * 4 + i;
        if (r < M) {
            float4 c;
            c.x = acc[i][0]; c.y = acc[i][1]; c.z = acc[i][2]; c.w = acc[i][3];
            if (ACCUM) {
                const float4 ci = *(const float4*)(Cin + (size_t)r * ldc + n0 + tx * 4);
                c.x += ci.x; c.y += ci.y; c.z += ci.z; c.w += ci.w;
            }
            if (BIAS) { c.x += bb.x; c.y += bb.y; c.z += bb.z; c.w += bb.w; }
            if (SILU) { c.x = silu_f(c.x); c.y = silu_f(c.y); c.z = silu_f(c.z); c.w = silu_f(c.w); }
            *(float4*)(Cout + (size_t)r * ldc + n0 + tx * 4) = c;
        }
    }
}

// ---------------- launcher ----------------
// Workspace budget (fp32 floats): deg N + dinv N + nrm E + T N*128 + 2x N*512
// = 0.2 + 0.2 + 1.6 + 25.6 + 204.8 MB = ~232.4 MB  (kept under 256 MiB).

extern "C" void kernel_launch(void* const* d_in, const int* in_sizes, int n_in,
                              void* d_out, int out_size, void* d_ws, size_t ws_size,
                              hipStream_t stream)
{
    const float* x      = (const float*)d_in[0];
    const int*   ei     = (const int*)  d_in[1];
    const float* in_w   = (const float*)d_in[2];
    const float* in_b   = (const float*)d_in[3];
    const float* conv_w = (const float*)d_in[4];
    const float* conv_b = (const float*)d_in[5];
    const float* out_w  = (const float*)d_in[6];
    const float* out_b  = (const float*)d_in[7];

    const int N = in_sizes[0] / CH_IN;   // 50000
    const int E = in_sizes[1] / 2;       // 400000
    const int* row = ei;
    const int* col = ei + E;

    float* ws   = (float*)d_ws;
    float* deg  = ws;                          // [N]
    float* dinv = deg  + N;                    // [N]
    float* nrm  = dinv + N;                    // [E]
    float* T    = nrm  + E;                    // [N*TCH]
    float* h    = T    + (size_t)N * TCH;      // [N*H]
    float* U    = h    + (size_t)N * CH_H;     // [N*H]

    hipMemsetAsync(deg, 0, (size_t)N * sizeof(float), stream);
    deg_kernel <<<(E + 255) / 256, 256, 0, stream>>>(row, deg, E);
    dinv_kernel<<<(N + 255) / 256, 256, 0, stream>>>(deg, dinv, N);
    norm_kernel<<<(E + 255) / 256, 256, 0, stream>>>(row, col, dinv, nrm, E);

    const int mtiles = (N + 63) / 64;
    const dim3 blk(256);

    // h = silu(x @ in_w + in_b)
    gemm_kernel<0, 1, 1><<<dim3(CH_H / 64, mtiles), blk, 0, stream>>>(
        x, CH_IN, in_w, CH_H, nullptr, h, CH_H, in_b, N, CH_H, CH_IN);

    for (int l = 0; l < 2; ++l) {
        const float* W0 = conv_w + ((size_t)(l * 2 + 0)) * CH_H * CH_H;
        const float* W1 = conv_w + ((size_t)(l * 2 + 1)) * CH_H * CH_H;
        const float* bl = conv_b + (size_t)l * CH_H;

        // U = Lhat @ (h @ W1) == (Lhat @ h) @ W1, chunked over columns
        hipMemsetAsync(U, 0, (size_t)N * CH_H * sizeof(float), stream);
        for (int c = 0; c < CH_H / TCH; ++c) {
            gemm_kernel<0, 0, 0><<<dim3(TCH / 64, mtiles), blk, 0, stream>>>(
                h, CH_H, W1 + c * TCH, CH_H, nullptr, T, TCH, nullptr, N, TCH, CH_H);
            prop_chunk_kernel<<<(E + 7) / 8, blk, 0, stream>>>(
                row, col, nrm, T, U, E, c * TCH);
        }

        // U = silu(h @ W0 + U + bl)   (in-place Cin == Cout)
        gemm_kernel<1, 1, 1><<<dim3(CH_H / 64, mtiles), blk, 0, stream>>>(
            h, CH_H, W0, CH_H, U, U, CH_H, bl, N, CH_H, CH_H);

        // ping-pong
        float* tmp = h; h = U; U = tmp;
    }

    // out = h @ out_w + out_b
    gemm_kernel<0, 1, 0><<<dim3(CH_OUT / 64, mtiles), blk, 0, stream>>>(
        h, CH_H, out_w, CH_OUT, nullptr, (float*)d_out, CH_OUT, out_b, N, CH_OUT, CH_H);
}

// Round 3
// 2651.935 us; speedup vs baseline: 2.8690x; 2.8690x over previous
//
#include <hip/hip_runtime.h>
#include <cmath>

#define CH_H   512
#define CH_IN  256
#define CH_OUT 256
#define TCH    128   // column chunk for the W1/prop pipeline

__device__ __forceinline__ float silu_f(float v) { return v / (1.0f + __expf(-v)); }

// ---------------- degree + in-degree histogram ----------------

__global__ void hist_kernel(const int* __restrict__ row, const int* __restrict__ col,
                            float* __restrict__ deg, int* __restrict__ cnt, int E) {
    int e = blockIdx.x * blockDim.x + threadIdx.x;
    if (e < E) {
        atomicAdd(&deg[row[e]], 1.0f);   // out-degree by source (reference's deg)
        atomicAdd(&cnt[col[e]], 1);      // in-degree by dest (CSR row sizes)
    }
}

__global__ void dinv_kernel(const float* __restrict__ deg, float* __restrict__ dinv, int n) {
    int i = blockIdx.x * blockDim.x + threadIdx.x;
    if (i < n) {
        float d = deg[i];
        dinv[i] = d > 0.0f ? rsqrtf(fmaxf(d, 1e-12f)) : 0.0f;
    }
}

// ---------------- single-block exclusive scan: cnt[N] -> ptr[N+1], ptr2[N] ----------------

__global__ __launch_bounds__(1024) void scan_kernel(const int* __restrict__ cnt,
                                                    int* __restrict__ ptr,
                                                    int* __restrict__ ptr2, int n) {
    __shared__ int smem[1024];
    __shared__ int carry_s;
    const int tid = threadIdx.x;
    if (tid == 0) carry_s = 0;
    __syncthreads();
    for (int base = 0; base < n; base += 1024) {
        int i = base + tid;
        int v = (i < n) ? cnt[i] : 0;
        smem[tid] = v;
        __syncthreads();
        for (int off = 1; off < 1024; off <<= 1) {
            int t = (tid >= off) ? smem[tid - off] : 0;
            __syncthreads();
            smem[tid] += t;
            __syncthreads();
        }
        int carry = carry_s;
        int exc = smem[tid] - v + carry;
        if (i < n) { ptr[i] = exc; ptr2[i] = exc; }
        int total = smem[1023];
        __syncthreads();
        if (tid == 0) carry_s = carry + total;
        __syncthreads();
    }
    if (tid == 0) ptr[n] = carry_s;
}

// ---------------- scatter edges into CSR (dest-sorted) ----------------

__global__ void scatter_kernel(const int* __restrict__ row, const int* __restrict__ col,
                               const float* __restrict__ dinv, int* __restrict__ ptr2,
                               int* __restrict__ esrc, float* __restrict__ ew, int E) {
    int e = blockIdx.x * blockDim.x + threadIdx.x;
    if (e >= E) return;
    int r = row[e], c = col[e];
    int pos = atomicAdd(&ptr2[c], 1);
    esrc[pos] = r;
    ew[pos]   = -dinv[r] * dinv[c];
}

// ---------------- gather prop: U[node, coff:coff+TCH] = sum_in w * T[src, :] ----------------
// 256 threads/block = 8 nodes/block, 32 threads (float4 each) per node. No atomics.

__global__ __launch_bounds__(256) void gather_chunk_kernel(
    const int* __restrict__ ptr, const int* __restrict__ esrc,
    const float* __restrict__ ew, const float* __restrict__ T,
    float* __restrict__ U, int N_, int coff)
{
    int t = threadIdx.x;
    int node = blockIdx.x * 8 + (t >> 5);
    if (node >= N_) return;
    int q = t & 31;
    float4 acc = make_float4(0.f, 0.f, 0.f, 0.f);
    const int i1 = ptr[node + 1];
    for (int i = ptr[node]; i < i1; ++i) {
        int s   = esrc[i];
        float w = ew[i];
        const float4 tv = *(const float4*)(T + (size_t)s * TCH + q * 4);
        acc.x += w * tv.x; acc.y += w * tv.y; acc.z += w * tv.z; acc.w += w * tv.w;
    }
    *(float4*)(U + (size_t)node * CH_H + coff + q * 4) = acc;
}

// ---------------- fp32 tiled GEMM with fused epilogue ----------------

template<int ACCUM, int BIAS, int SILU>
__global__ __launch_bounds__(256) void gemm_kernel(
    const float* __restrict__ A, int lda,
    const float* __restrict__ B, int ldb,
    const float* __restrict__ Cin, float* __restrict__ Cout, int ldc,
    const float* __restrict__ bias, int M, int Nn, int K)
{
    __shared__ float As[16][64];   // [k][row]
    __shared__ float Bs[16][64];   // [k][col]

    const int t  = threadIdx.x;
    const int m0 = blockIdx.y * 64;
    const int n0 = blockIdx.x * 64;

    const int la_r = t >> 2;          // 0..63 row within tile
    const int la_k = (t & 3) * 4;     // 0,4,8,12
    const int lb_k = t >> 4;          // 0..15
    const int lb_n = (t & 15) * 4;    // 0..60

    const int ty = t >> 4;            // rows ty*4..ty*4+3
    const int tx = t & 15;            // cols tx*4..tx*4+3

    float acc[4][4] = {};

    for (int k0 = 0; k0 < K; k0 += 16) {
        float4 av;
        const int ar = m0 + la_r;
        if (ar < M) av = *(const float4*)(A + (size_t)ar * lda + k0 + la_k);
        else        av = make_float4(0.f, 0.f, 0.f, 0.f);
        As[la_k + 0][la_r] = av.x;
        As[la_k + 1][la_r] = av.y;
        As[la_k + 2][la_r] = av.z;
        As[la_k + 3][la_r] = av.w;

        const float4 bv = *(const float4*)(B + (size_t)(k0 + lb_k) * ldb + n0 + lb_n);
        *(float4*)&Bs[lb_k][lb_n] = bv;

        __syncthreads();

        #pragma unroll
        for (int k = 0; k < 16; ++k) {
            const float4 a = *(const float4*)&As[k][ty * 4];
            const float4 b = *(const float4*)&Bs[k][tx * 4];
            acc[0][0] += a.x * b.x; acc[0][1] += a.x * b.y; acc[0][2] += a.x * b.z; acc[0][3] += a.x * b.w;
            acc[1][0] += a.y * b.x; acc[1][1] += a.y * b.y; acc[1][2] += a.y * b.z; acc[1][3] += a.y * b.w;
            acc[2][0] += a.z * b.x; acc[2][1] += a.z * b.y; acc[2][2] += a.z * b.z; acc[2][3] += a.z * b.w;
            acc[3][0] += a.w * b.x; acc[3][1] += a.w * b.y; acc[3][2] += a.w * b.z; acc[3][3] += a.w * b.w;
        }
        __syncthreads();
    }

    float4 bb = make_float4(0.f, 0.f, 0.f, 0.f);
    if (BIAS) bb = *(const float4*)(bias + n0 + tx * 4);

    #pragma unroll
    for (int i = 0; i < 4; ++i) {
        const int r = m0 + ty * 4 + i;
        if (r < M) {
            float4 c;
            c.x = acc[i][0]; c.y = acc[i][1]; c.z = acc[i][2]; c.w = acc[i][3];
            if (ACCUM) {
                const float4 ci = *(const float4*)(Cin + (size_t)r * ldc + n0 + tx * 4);
                c.x += ci.x; c.y += ci.y; c.z += ci.z; c.w += ci.w;
            }
            if (BIAS) { c.x += bb.x; c.y += bb.y; c.z += bb.z; c.w += bb.w; }
            if (SILU) { c.x = silu_f(c.x); c.y = silu_f(c.y); c.z = silu_f(c.z); c.w = silu_f(c.w); }
            *(float4*)(Cout + (size_t)r * ldc + n0 + tx * 4) = c;
        }
    }
}

// ---------------- launcher ----------------
// Workspace: h(102.4) U(102.4) T(25.6) deg(0.2) dinv(0.2) ew(1.6) cnt(0.2)
//            ptr(0.2) ptr2(0.2) esrc(1.6)  ~= 234.6 MB  (< 256 MiB)

extern "C" void kernel_launch(void* const* d_in, const int* in_sizes, int n_in,
                              void* d_out, int out_size, void* d_ws, size_t ws_size,
                              hipStream_t stream)
{
    const float* x      = (const float*)d_in[0];
    const int*   ei     = (const int*)  d_in[1];
    const float* in_w   = (const float*)d_in[2];
    const float* in_b   = (const float*)d_in[3];
    const float* conv_w = (const float*)d_in[4];
    const float* conv_b = (const float*)d_in[5];
    const float* out_w  = (const float*)d_in[6];
    const float* out_b  = (const float*)d_in[7];

    const int N = in_sizes[0] / CH_IN;   // 50000
    const int E = in_sizes[1] / 2;       // 400000
    const int* row = ei;
    const int* col = ei + E;

    char* p = (char*)d_ws;
    float* h    = (float*)p;  p += (size_t)N * CH_H * sizeof(float);
    float* U    = (float*)p;  p += (size_t)N * CH_H * sizeof(float);
    float* T    = (float*)p;  p += (size_t)N * TCH  * sizeof(float);
    float* deg  = (float*)p;  p += (size_t)N * sizeof(float);
    float* dinv = (float*)p;  p += (size_t)N * sizeof(float);
    float* ew   = (float*)p;  p += (size_t)E * sizeof(float);
    int*   cnt  = (int*)p;    p += (size_t)N * sizeof(int);
    int*   ptr  = (int*)p;    p += (size_t)(N + 4) * sizeof(int);
    int*   ptr2 = (int*)p;    p += (size_t)N * sizeof(int);
    int*   esrc = (int*)p;    p += (size_t)E * sizeof(int);

    hipMemsetAsync(deg, 0, (size_t)N * sizeof(float), stream);
    hipMemsetAsync(cnt, 0, (size_t)N * sizeof(int), stream);
    hist_kernel<<<(E + 255) / 256, 256, 0, stream>>>(row, col, deg, cnt, E);
    dinv_kernel<<<(N + 255) / 256, 256, 0, stream>>>(deg, dinv, N);
    scan_kernel<<<1, 1024, 0, stream>>>(cnt, ptr, ptr2, N);
    scatter_kernel<<<(E + 255) / 256, 256, 0, stream>>>(row, col, dinv, ptr2, esrc, ew, E);

    const int mtiles = (N + 63) / 64;
    const dim3 blk(256);

    // h = silu(x @ in_w + in_b)
    gemm_kernel<0, 1, 1><<<dim3(CH_H / 64, mtiles), blk, 0, stream>>>(
        x, CH_IN, in_w, CH_H, nullptr, h, CH_H, in_b, N, CH_H, CH_IN);

    for (int l = 0; l < 2; ++l) {
        const float* W0 = conv_w + ((size_t)(l * 2 + 0)) * CH_H * CH_H;
        const float* W1 = conv_w + ((size_t)(l * 2 + 1)) * CH_H * CH_H;
        const float* bl = conv_b + (size_t)l * CH_H;

        // U[:, chunk] = Lhat @ (h @ W1[:, chunk]), 4 chunks of 128 cols
        for (int c = 0; c < CH_H / TCH; ++c) {
            gemm_kernel<0, 0, 0><<<dim3(TCH / 64, mtiles), blk, 0, stream>>>(
                h, CH_H, W1 + c * TCH, CH_H, nullptr, T, TCH, nullptr, N, TCH, CH_H);
            gather_chunk_kernel<<<(N + 7) / 8, blk, 0, stream>>>(
                ptr, esrc, ew, T, U, N, c * TCH);
        }

        // U = silu(h @ W0 + U + bl)   (in-place Cin == Cout)
        gemm_kernel<1, 1, 1><<<dim3(CH_H / 64, mtiles), blk, 0, stream>>>(
            h, CH_H, W0, CH_H, U, U, CH_H, bl, N, CH_H, CH_H);

        // ping-pong
        float* tmp = h; h = U; U = tmp;
    }

    // out = h @ out_w + out_b
    gemm_kernel<0, 1, 0><<<dim3(CH_OUT / 64, mtiles), blk, 0, stream>>>(
        h, CH_H, out_w, CH_OUT, nullptr, (float*)d_out, CH_OUT, out_b, N, CH_OUT, CH_H);
}

// Round 4
// 628.581 us; speedup vs baseline: 12.1039x; 4.2189x over previous
//
#include <hip/hip_runtime.h>

#define H512 512

typedef short bf16x8 __attribute__((ext_vector_type(8)));
typedef float f32x4  __attribute__((ext_vector_type(4)));

__device__ __forceinline__ float silu_f(float v) { return v / (1.0f + __expf(-v)); }

__device__ __forceinline__ short f2bf(float f) {   // RNE float -> bf16 bits
    unsigned u = __float_as_uint(f);
    u = (u + 0x7FFFu + ((u >> 16) & 1u)) >> 16;
    return (short)u;
}
__device__ __forceinline__ float bf2f(short s) {
    return __uint_as_float(((unsigned)(unsigned short)s) << 16);
}

// ---------------- CSR build ----------------

__global__ void hist_kernel(const int* __restrict__ row, const int* __restrict__ col,
                            float* __restrict__ deg, int* __restrict__ cnt, int E) {
    int e = blockIdx.x * blockDim.x + threadIdx.x;
    if (e < E) {
        atomicAdd(&deg[row[e]], 1.0f);
        atomicAdd(&cnt[col[e]], 1);
    }
}

__global__ void dinv_kernel(const float* __restrict__ deg, float* __restrict__ dinv, int n) {
    int i = blockIdx.x * blockDim.x + threadIdx.x;
    if (i < n) {
        float d = deg[i];
        dinv[i] = d > 0.0f ? rsqrtf(fmaxf(d, 1e-12f)) : 0.0f;
    }
}

__global__ __launch_bounds__(1024) void scan_kernel(const int* __restrict__ cnt,
                                                    int* __restrict__ ptr,
                                                    int* __restrict__ ptr2, int n) {
    __shared__ int smem[1024];
    __shared__ int carry_s;
    const int tid = threadIdx.x;
    if (tid == 0) carry_s = 0;
    __syncthreads();
    for (int base = 0; base < n; base += 1024) {
        int i = base + tid;
        int v = (i < n) ? cnt[i] : 0;
        smem[tid] = v;
        __syncthreads();
        for (int off = 1; off < 1024; off <<= 1) {
            int t = (tid >= off) ? smem[tid - off] : 0;
            __syncthreads();
            smem[tid] += t;
            __syncthreads();
        }
        int carry = carry_s;
        int exc = smem[tid] - v + carry;
        if (i < n) { ptr[i] = exc; ptr2[i] = exc; }
        int total = smem[1023];
        __syncthreads();
        if (tid == 0) carry_s = carry + total;
        __syncthreads();
    }
    if (tid == 0) ptr[n] = carry_s;
}

__global__ void scatter_kernel(const int* __restrict__ row, const int* __restrict__ col,
                               const float* __restrict__ dinv, int* __restrict__ ptr2,
                               int* __restrict__ esrc, float* __restrict__ ew, int E) {
    int e = blockIdx.x * blockDim.x + threadIdx.x;
    if (e >= E) return;
    int r = row[e], c = col[e];
    int pos = atomicAdd(&ptr2[c], 1);
    esrc[pos] = r;
    ew[pos]   = -dinv[r] * dinv[c];
}

// ---------------- converts ----------------

// Wt[n][k] = bf16(W[k][n])  (transposed weight for contiguous B-fragments)
__global__ void wt_kernel(const float* __restrict__ W, short* __restrict__ Wt, int K, int Nw) {
    int tid = blockIdx.x * blockDim.x + threadIdx.x;
    if (tid >= K * Nw) return;
    int n = tid / K, k = tid - n * K;
    Wt[(size_t)n * K + k] = f2bf(W[(size_t)k * Nw + n]);
}

// xb[MPAD][256] = bf16(x), zero-padded rows
__global__ void xconv_kernel(const float* __restrict__ x, short* __restrict__ xb,
                             int Nreal, int Mpad) {
    int tid = blockIdx.x * blockDim.x + threadIdx.x;
    if (tid >= Mpad * 32) return;
    int r = tid >> 5, c8 = (tid & 31) * 8;
    bf16x8 o = {0, 0, 0, 0, 0, 0, 0, 0};
    if (r < Nreal) {
        const float4 f0 = *(const float4*)(x + (size_t)r * 256 + c8);
        const float4 f1 = *(const float4*)(x + (size_t)r * 256 + c8 + 4);
        o[0] = f2bf(f0.x); o[1] = f2bf(f0.y); o[2] = f2bf(f0.z); o[3] = f2bf(f0.w);
        o[4] = f2bf(f1.x); o[5] = f2bf(f1.y); o[6] = f2bf(f1.z); o[7] = f2bf(f1.w);
    }
    *(bf16x8*)(xb + (size_t)r * 256 + c8) = o;
}

// ---------------- gather prop: U[node,:] = sum_in w * T[src,:]  (bf16 in/out) ----------------
// 4 nodes/block, 64 lanes per node (8 bf16 each), fp32 accumulate, no atomics.

__global__ __launch_bounds__(256) void gather_kernel(
    const int* __restrict__ ptr, const int* __restrict__ esrc,
    const float* __restrict__ ew, const short* __restrict__ T,
    short* __restrict__ U, int N_)
{
    int t = threadIdx.x;
    int node = blockIdx.x * 4 + (t >> 6);
    if (node >= N_) return;
    int q = (t & 63) * 8;
    float acc[8] = {0.f, 0.f, 0.f, 0.f, 0.f, 0.f, 0.f, 0.f};
    const int i1 = ptr[node + 1];
    for (int i = ptr[node]; i < i1; ++i) {
        int s   = esrc[i];
        float w = ew[i];
        bf16x8 tv = *(const bf16x8*)(T + (size_t)s * H512 + q);
        #pragma unroll
        for (int j = 0; j < 8; ++j) acc[j] += w * bf2f(tv[j]);
    }
    bf16x8 o;
    #pragma unroll
    for (int j = 0; j < 8; ++j) o[j] = f2bf(acc[j]);
    *(bf16x8*)(U + (size_t)node * H512 + q) = o;
}

// ---------------- bf16 MFMA GEMM ----------------
// Cout[M,Nw] = op( (ACCUM? bf2f(Cin) : 0) + A @ Bt^T + (BIAS? bias : 0) ), op=SiLU opt.
// A: bf16 [MPAD][lda], Bt: bf16 [Nw][ldb] (transposed weight), tile 128x128, BK=64.
// 256 threads = 4 waves (2x2), each wave 64x64 = 4x4 frags of 16x16x32 MFMA.
// LDS staged via global_load_lds(16B) with XOR-swizzled SOURCE (linear dest),
// reads swizzled: byte ^= ((row&7)<<4)  -> ~2-way conflicts (free).

template<int ACCUM, int BIAS, int SILU, int F32OUT>
__global__ __launch_bounds__(256) void mfma_gemm(
    const short* __restrict__ A, int lda,
    const short* __restrict__ Bt, int ldb,
    const short* __restrict__ Cin, void* __restrict__ Cout, int ldc,
    const float* __restrict__ bias, int Mreal, int K)
{
    __shared__ alignas(16) short As[128 * 64];
    __shared__ alignas(16) short Bs[128 * 64];

    const int t    = threadIdx.x;
    const int lane = t & 63;
    const int wid  = t >> 6;
    const int m0   = blockIdx.y * 128;
    const int n0   = blockIdx.x * 128;
    const int wm   = wid >> 1;
    const int wn   = wid & 1;

    // staging geometry: each wave-load covers 8 rows x 128B; lane -> (row, 16B slot)
    const int srow  = lane >> 3;            // 0..7
    const int scol  = (lane & 7) * 16;      // byte col, 0..112
    const int corig = scol ^ (srow << 4);   // inverse-swizzled source byte col
    const int cel   = corig >> 1;           // source element offset

    f32x4 acc[4][4];
    #pragma unroll
    for (int m = 0; m < 4; ++m)
        #pragma unroll
        for (int n = 0; n < 4; ++n)
            acc[m][n] = (f32x4){0.f, 0.f, 0.f, 0.f};

    const int r = lane & 15;
    const int g = lane >> 4;

    for (int k0 = 0; k0 < K; k0 += 64) {
        #pragma unroll
        for (int i = 0; i < 4; ++i) {
            const int r0 = (wid * 4 + i) * 8;
            const short* ga = A  + (size_t)(m0 + r0 + srow) * lda + (k0 + cel);
            __builtin_amdgcn_global_load_lds(
                (const __attribute__((address_space(1))) void*)ga,
                (__attribute__((address_space(3))) void*)(As + r0 * 64), 16, 0, 0);
            const short* gb = Bt + (size_t)(n0 + r0 + srow) * ldb + (k0 + cel);
            __builtin_amdgcn_global_load_lds(
                (const __attribute__((address_space(1))) void*)gb,
                (__attribute__((address_space(3))) void*)(Bs + r0 * 64), 16, 0, 0);
        }
        asm volatile("s_waitcnt vmcnt(0)" ::: "memory");
        __syncthreads();

        #pragma unroll
        for (int ks = 0; ks < 2; ++ks) {
            bf16x8 af[4], bfr[4];
            #pragma unroll
            for (int m = 0; m < 4; ++m) {
                const int rowA = wm * 64 + m * 16 + r;
                const int cb   = (ks * 64 + g * 16) ^ ((rowA & 7) << 4);
                af[m] = *(const bf16x8*)((const char*)As + rowA * 128 + cb);
            }
            #pragma unroll
            for (int n = 0; n < 4; ++n) {
                const int rowB = wn * 64 + n * 16 + r;
                const int cb   = (ks * 64 + g * 16) ^ ((rowB & 7) << 4);
                bfr[n] = *(const bf16x8*)((const char*)Bs + rowB * 128 + cb);
            }
            #pragma unroll
            for (int m = 0; m < 4; ++m)
                #pragma unroll
                for (int n = 0; n < 4; ++n)
                    acc[m][n] = __builtin_amdgcn_mfma_f32_16x16x32_bf16(
                        af[m], bfr[n], acc[m][n], 0, 0, 0);
        }
        __syncthreads();
    }

    // epilogue: C/D frag mapping col = lane&15, row = (lane>>4)*4 + j  (m89)
    #pragma unroll
    for (int n = 0; n < 4; ++n) {
        const int col = n0 + wn * 64 + n * 16 + r;
        float bb = 0.f;
        if (BIAS) bb = bias[col];
        #pragma unroll
        for (int m = 0; m < 4; ++m) {
            const int row0 = m0 + wm * 64 + m * 16 + g * 4;
            #pragma unroll
            for (int j = 0; j < 4; ++j) {
                const int rr = row0 + j;
                float v = acc[m][n][j];
                if (ACCUM) v += bf2f(Cin[(size_t)rr * ldc + col]);
                if (BIAS)  v += bb;
                if (SILU)  v = silu_f(v);
                if (F32OUT) {
                    if (rr < Mreal) ((float*)Cout)[(size_t)rr * ldc + col] = v;
                } else {
                    ((short*)Cout)[(size_t)rr * ldc + col] = f2bf(v);
                }
            }
        }
    }
}

// ---------------- launcher ----------------
// Workspace (MPAD=50048): h0,h1,T,U bf16 51.25 MB each = 205.0 MB
//   + weights bf16 2.62 MB + CSR/misc 4.2 MB  ~= 211.8 MB.  xb aliases T.

extern "C" void kernel_launch(void* const* d_in, const int* in_sizes, int n_in,
                              void* d_out, int out_size, void* d_ws, size_t ws_size,
                              hipStream_t stream)
{
    const float* x      = (const float*)d_in[0];
    const int*   ei     = (const int*)  d_in[1];
    const float* in_w   = (const float*)d_in[2];
    const float* in_b   = (const float*)d_in[3];
    const float* conv_w = (const float*)d_in[4];
    const float* conv_b = (const float*)d_in[5];
    const float* out_w  = (const float*)d_in[6];
    const float* out_b  = (const float*)d_in[7];

    const int N = in_sizes[0] / 256;           // 50000
    const int E = in_sizes[1] / 2;             // 400000
    const int MPAD = ((N + 127) / 128) * 128;  // 50048
    const int* row = ei;
    const int* col = ei + E;

    char* p = (char*)d_ws;
    short* h0 = (short*)p; p += (size_t)MPAD * H512 * 2;
    short* h1 = (short*)p; p += (size_t)MPAD * H512 * 2;
    short* T  = (short*)p; p += (size_t)MPAD * H512 * 2;
    short* U  = (short*)p; p += (size_t)MPAD * H512 * 2;
    short* xb = T;  // alias: xb dead before T is first written
    short* wti = (short*)p; p += (size_t)512 * 256 * 2;      // in_w^T  [512][256]
    short* wtc = (short*)p; p += (size_t)4 * 512 * 512 * 2;  // conv_w^T [4][512][512]
    short* wto = (short*)p; p += (size_t)256 * 512 * 2;      // out_w^T [256][512]
    float* deg  = (float*)p; p += (size_t)N * 4;
    float* dinv = (float*)p; p += (size_t)N * 4;
    float* ew   = (float*)p; p += (size_t)E * 4;
    int*   cnt  = (int*)p;   p += (size_t)N * 4;
    int*   ptr  = (int*)p;   p += (size_t)(N + 4) * 4;
    int*   ptr2 = (int*)p;   p += (size_t)N * 4;
    int*   esrc = (int*)p;   p += (size_t)E * 4;

    // CSR build
    hipMemsetAsync(deg, 0, (size_t)N * sizeof(float), stream);
    hipMemsetAsync(cnt, 0, (size_t)N * sizeof(int), stream);
    hist_kernel<<<(E + 255) / 256, 256, 0, stream>>>(row, col, deg, cnt, E);
    dinv_kernel<<<(N + 255) / 256, 256, 0, stream>>>(deg, dinv, N);
    scan_kernel<<<1, 1024, 0, stream>>>(cnt, ptr, ptr2, N);
    scatter_kernel<<<(E + 255) / 256, 256, 0, stream>>>(row, col, dinv, ptr2, esrc, ew, E);

    // weight/x converts
    wt_kernel<<<(256 * 512 + 255) / 256, 256, 0, stream>>>(in_w, wti, 256, 512);
    for (int i = 0; i < 4; ++i)
        wt_kernel<<<(512 * 512 + 255) / 256, 256, 0, stream>>>(
            conv_w + (size_t)i * 512 * 512, wtc + (size_t)i * 512 * 512, 512, 512);
    wt_kernel<<<(512 * 256 + 255) / 256, 256, 0, stream>>>(out_w, wto, 512, 256);
    xconv_kernel<<<(MPAD * 32 + 255) / 256, 256, 0, stream>>>(x, xb, N, MPAD);

    const int mt = MPAD / 128;

    // h0 = silu(x @ in_w + in_b)
    mfma_gemm<0, 1, 1, 0><<<dim3(4, mt), 256, 0, stream>>>(
        xb, 256, wti, 256, nullptr, h0, H512, in_b, N, 256);

    short* hc = h0;
    short* hn = h1;
    for (int l = 0; l < 2; ++l) {
        // T = hc @ W1
        mfma_gemm<0, 0, 0, 0><<<dim3(4, mt), 256, 0, stream>>>(
            hc, H512, wtc + (size_t)(l * 2 + 1) * 512 * 512, 512,
            nullptr, T, H512, nullptr, N, 512);
        // U = Lhat @ T   (gather, no atomics)
        gather_kernel<<<(N + 3) / 4, 256, 0, stream>>>(ptr, esrc, ew, T, U, N);
        // hn = silu(hc @ W0 + U + b)
        mfma_gemm<1, 1, 1, 0><<<dim3(4, mt), 256, 0, stream>>>(
            hc, H512, wtc + (size_t)(l * 2 + 0) * 512 * 512, 512,
            U, hn, H512, conv_b + (size_t)l * H512, N, 512);
        short* tmp = hc; hc = hn; hn = tmp;
    }

    // out = hc @ out_w + out_b   (fp32, guarded)
    mfma_gemm<0, 1, 0, 1><<<dim3(2, mt), 256, 0, stream>>>(
        hc, H512, wto, 512, nullptr, d_out, 256, out_b, N, 512);
}

// Round 5
// 542.737 us; speedup vs baseline: 14.0184x; 1.1582x over previous
//
#include <hip/hip_runtime.h>

#define H512 512

typedef short bf16x8 __attribute__((ext_vector_type(8)));
typedef float f32x4  __attribute__((ext_vector_type(4)));

__device__ __forceinline__ float silu_f(float v) { return v / (1.0f + __expf(-v)); }

__device__ __forceinline__ short f2bf(float f) {   // RNE float -> bf16 bits
    unsigned u = __float_as_uint(f);
    u = (u + 0x7FFFu + ((u >> 16) & 1u)) >> 16;
    return (short)u;
}
__device__ __forceinline__ float bf2f(short s) {
    return __uint_as_float(((unsigned)(unsigned short)s) << 16);
}

// ---------------- CSR build ----------------

__global__ void hist_kernel(const int* __restrict__ row, const int* __restrict__ col,
                            float* __restrict__ deg, int* __restrict__ cnt, int E) {
    int e = blockIdx.x * blockDim.x + threadIdx.x;
    if (e < E) {
        atomicAdd(&deg[row[e]], 1.0f);
        atomicAdd(&cnt[col[e]], 1);
    }
}

__global__ void dinv_kernel(const float* __restrict__ deg, float* __restrict__ dinv, int n) {
    int i = blockIdx.x * blockDim.x + threadIdx.x;
    if (i < n) {
        float d = deg[i];
        dinv[i] = d > 0.0f ? rsqrtf(fmaxf(d, 1e-12f)) : 0.0f;
    }
}

// ---- 3-phase multi-block exclusive scan of cnt[n] -> ptr[n+1], ptr2[n] ----

__global__ __launch_bounds__(256) void bsum_kernel(const int* __restrict__ cnt,
                                                   int* __restrict__ bsum, int n) {
    __shared__ int s[4];
    int i = blockIdx.x * 256 + threadIdx.x;
    int v = (i < n) ? cnt[i] : 0;
    #pragma unroll
    for (int off = 32; off; off >>= 1) v += __shfl_down(v, off, 64);
    if ((threadIdx.x & 63) == 0) s[threadIdx.x >> 6] = v;
    __syncthreads();
    if (threadIdx.x == 0) bsum[blockIdx.x] = s[0] + s[1] + s[2] + s[3];
}

__global__ __launch_bounds__(256) void bscan_kernel(const int* __restrict__ bsum,
                                                    int* __restrict__ boff, int B) {
    __shared__ int s[256];
    int tid = threadIdx.x;
    int v = (tid < B) ? bsum[tid] : 0;
    s[tid] = v;
    __syncthreads();
    #pragma unroll
    for (int off = 1; off < 256; off <<= 1) {
        int t = (tid >= off) ? s[tid - off] : 0;
        __syncthreads();
        s[tid] += t;
        __syncthreads();
    }
    if (tid < B) boff[tid] = s[tid] - v;   // exclusive
}

__global__ __launch_bounds__(256) void cscan_kernel(const int* __restrict__ cnt,
                                                    const int* __restrict__ boff,
                                                    int* __restrict__ ptr,
                                                    int* __restrict__ ptr2, int n, int B) {
    __shared__ int s[256];
    int b = blockIdx.x, tid = threadIdx.x;
    int i = b * 256 + tid;
    int v = (i < n) ? cnt[i] : 0;
    s[tid] = v;
    __syncthreads();
    #pragma unroll
    for (int off = 1; off < 256; off <<= 1) {
        int t = (tid >= off) ? s[tid - off] : 0;
        __syncthreads();
        s[tid] += t;
        __syncthreads();
    }
    int exc = boff[b] + s[tid] - v;
    if (i < n) { ptr[i] = exc; ptr2[i] = exc; }
    if (b == B - 1 && tid == 255) ptr[n] = exc + v;  // grand total
}

__global__ void scatter_kernel(const int* __restrict__ row, const int* __restrict__ col,
                               const float* __restrict__ dinv, int* __restrict__ ptr2,
                               int* __restrict__ esrc, float* __restrict__ ew, int E) {
    int e = blockIdx.x * blockDim.x + threadIdx.x;
    if (e >= E) return;
    int r = row[e], c = col[e];
    int pos = atomicAdd(&ptr2[c], 1);
    esrc[pos] = r;
    ew[pos]   = -dinv[r] * dinv[c];
}

// ---------------- converts ----------------

// Wt[n][k] = bf16(W[k][n])  (transposed weight for contiguous B-fragments)
__global__ void wt_kernel(const float* __restrict__ W, short* __restrict__ Wt, int K, int Nw) {
    int tid = blockIdx.x * blockDim.x + threadIdx.x;
    if (tid >= K * Nw) return;
    int n = tid / K, k = tid - n * K;
    Wt[(size_t)n * K + k] = f2bf(W[(size_t)k * Nw + n]);
}

// xb[MPAD][256] = bf16(x), zero-padded rows
__global__ void xconv_kernel(const float* __restrict__ x, short* __restrict__ xb,
                             int Nreal, int Mpad) {
    int tid = blockIdx.x * blockDim.x + threadIdx.x;
    if (tid >= Mpad * 32) return;
    int r = tid >> 5, c8 = (tid & 31) * 8;
    bf16x8 o = {0, 0, 0, 0, 0, 0, 0, 0};
    if (r < Nreal) {
        const float4 f0 = *(const float4*)(x + (size_t)r * 256 + c8);
        const float4 f1 = *(const float4*)(x + (size_t)r * 256 + c8 + 4);
        o[0] = f2bf(f0.x); o[1] = f2bf(f0.y); o[2] = f2bf(f0.z); o[3] = f2bf(f0.w);
        o[4] = f2bf(f1.x); o[5] = f2bf(f1.y); o[6] = f2bf(f1.z); o[7] = f2bf(f1.w);
    }
    *(bf16x8*)(xb + (size_t)r * 256 + c8) = o;
}

// ---------------- gather prop: U[node,:] = sum_in w * T[src,:]  (bf16 in/out) ----------------

__global__ __launch_bounds__(256) void gather_kernel(
    const int* __restrict__ ptr, const int* __restrict__ esrc,
    const float* __restrict__ ew, const short* __restrict__ T,
    short* __restrict__ U, int N_)
{
    int t = threadIdx.x;
    int node = blockIdx.x * 4 + (t >> 6);
    if (node >= N_) return;
    int q = (t & 63) * 8;
    float acc[8] = {0.f, 0.f, 0.f, 0.f, 0.f, 0.f, 0.f, 0.f};
    const int i1 = ptr[node + 1];
    for (int i = ptr[node]; i < i1; ++i) {
        int s   = esrc[i];
        float w = ew[i];
        bf16x8 tv = *(const bf16x8*)(T + (size_t)s * H512 + q);
        #pragma unroll
        for (int j = 0; j < 8; ++j) acc[j] += w * bf2f(tv[j]);
    }
    bf16x8 o;
    #pragma unroll
    for (int j = 0; j < 8; ++j) o[j] = f2bf(acc[j]);
    *(bf16x8*)(U + (size_t)node * H512 + q) = o;
}

// ---------------- bf16 MFMA GEMM ----------------
// Cout[M,Nw] = op( (ACCUM? bf2f(Cin) : 0) + A @ Bt^T + (BIAS? bias : 0) ), op=SiLU opt.
// A: bf16 [MPAD][lda], Bt: bf16 [Nw][ldb] (transposed weight), tile 128x128, BK=64.
// LDS staged via global_load_lds(16B) with XOR-swizzled SOURCE (linear dest),
// reads swizzled: byte ^= ((row&7)<<4).

template<int ACCUM, int BIAS, int SILU, int F32OUT>
__global__ __launch_bounds__(256) void mfma_gemm(
    const short* __restrict__ A, int lda,
    const short* __restrict__ Bt, int ldb,
    const short* __restrict__ Cin, void* __restrict__ Cout, int ldc,
    const float* __restrict__ bias, int Mreal, int K)
{
    __shared__ alignas(16) short As[128 * 64];
    __shared__ alignas(16) short Bs[128 * 64];

    const int t    = threadIdx.x;
    const int lane = t & 63;
    const int wid  = t >> 6;
    const int m0   = blockIdx.y * 128;
    const int n0   = blockIdx.x * 128;
    const int wm   = wid >> 1;
    const int wn   = wid & 1;

    const int srow  = lane >> 3;            // 0..7
    const int scol  = (lane & 7) * 16;      // byte col, 0..112
    const int corig = scol ^ (srow << 4);   // inverse-swizzled source byte col
    const int cel   = corig >> 1;           // source element offset

    f32x4 acc[4][4];
    #pragma unroll
    for (int m = 0; m < 4; ++m)
        #pragma unroll
        for (int n = 0; n < 4; ++n)
            acc[m][n] = (f32x4){0.f, 0.f, 0.f, 0.f};

    const int r = lane & 15;
    const int g = lane >> 4;

    for (int k0 = 0; k0 < K; k0 += 64) {
        #pragma unroll
        for (int i = 0; i < 4; ++i) {
            const int r0 = (wid * 4 + i) * 8;
            const short* ga = A  + (size_t)(m0 + r0 + srow) * lda + (k0 + cel);
            __builtin_amdgcn_global_load_lds(
                (const __attribute__((address_space(1))) void*)ga,
                (__attribute__((address_space(3))) void*)(As + r0 * 64), 16, 0, 0);
            const short* gb = Bt + (size_t)(n0 + r0 + srow) * ldb + (k0 + cel);
            __builtin_amdgcn_global_load_lds(
                (const __attribute__((address_space(1))) void*)gb,
                (__attribute__((address_space(3))) void*)(Bs + r0 * 64), 16, 0, 0);
        }
        asm volatile("s_waitcnt vmcnt(0)" ::: "memory");
        __syncthreads();

        #pragma unroll
        for (int ks = 0; ks < 2; ++ks) {
            bf16x8 af[4], bfr[4];
            #pragma unroll
            for (int m = 0; m < 4; ++m) {
                const int rowA = wm * 64 + m * 16 + r;
                const int cb   = (ks * 64 + g * 16) ^ ((rowA & 7) << 4);
                af[m] = *(const bf16x8*)((const char*)As + rowA * 128 + cb);
            }
            #pragma unroll
            for (int n = 0; n < 4; ++n) {
                const int rowB = wn * 64 + n * 16 + r;
                const int cb   = (ks * 64 + g * 16) ^ ((rowB & 7) << 4);
                bfr[n] = *(const bf16x8*)((const char*)Bs + rowB * 128 + cb);
            }
            #pragma unroll
            for (int m = 0; m < 4; ++m)
                #pragma unroll
                for (int n = 0; n < 4; ++n)
                    acc[m][n] = __builtin_amdgcn_mfma_f32_16x16x32_bf16(
                        af[m], bfr[n], acc[m][n], 0, 0, 0);
        }
        __syncthreads();
    }

    // epilogue: C/D frag mapping col = lane&15, row = (lane>>4)*4 + j  (m89)
    #pragma unroll
    for (int n = 0; n < 4; ++n) {
        const int col = n0 + wn * 64 + n * 16 + r;
        float bb = 0.f;
        if (BIAS) bb = bias[col];
        #pragma unroll
        for (int m = 0; m < 4; ++m) {
            const int row0 = m0 + wm * 64 + m * 16 + g * 4;
            #pragma unroll
            for (int j = 0; j < 4; ++j) {
                const int rr = row0 + j;
                float v = acc[m][n][j];
                if (ACCUM) v += bf2f(Cin[(size_t)rr * ldc + col]);
                if (BIAS)  v += bb;
                if (SILU)  v = silu_f(v);
                if (F32OUT) {
                    if (rr < Mreal) ((float*)Cout)[(size_t)rr * ldc + col] = v;
                } else {
                    ((short*)Cout)[(size_t)rr * ldc + col] = f2bf(v);
                }
            }
        }
    }
}

// ---------------- launcher ----------------
// Workspace (MPAD=50048): h0,h1,T,U bf16 51.25 MB each = 205.0 MB
//   + weights bf16 2.62 MB + CSR/misc ~4.5 MB  ~= 212 MB.  xb aliases T.

extern "C" void kernel_launch(void* const* d_in, const int* in_sizes, int n_in,
                              void* d_out, int out_size, void* d_ws, size_t ws_size,
                              hipStream_t stream)
{
    const float* x      = (const float*)d_in[0];
    const int*   ei     = (const int*)  d_in[1];
    const float* in_w   = (const float*)d_in[2];
    const float* in_b   = (const float*)d_in[3];
    const float* conv_w = (const float*)d_in[4];
    const float* conv_b = (const float*)d_in[5];
    const float* out_w  = (const float*)d_in[6];
    const float* out_b  = (const float*)d_in[7];

    const int N = in_sizes[0] / 256;           // 50000
    const int E = in_sizes[1] / 2;             // 400000
    const int MPAD = ((N + 127) / 128) * 128;  // 50048
    const int* row = ei;
    const int* col = ei + E;

    char* p = (char*)d_ws;
    short* h0 = (short*)p; p += (size_t)MPAD * H512 * 2;
    short* h1 = (short*)p; p += (size_t)MPAD * H512 * 2;
    short* T  = (short*)p; p += (size_t)MPAD * H512 * 2;
    short* U  = (short*)p; p += (size_t)MPAD * H512 * 2;
    short* xb = T;  // alias: xb dead before T is first written
    short* wti = (short*)p; p += (size_t)512 * 256 * 2;      // in_w^T  [512][256]
    short* wtc = (short*)p; p += (size_t)4 * 512 * 512 * 2;  // conv_w^T [4][512][512]
    short* wto = (short*)p; p += (size_t)256 * 512 * 2;      // out_w^T [256][512]
    float* deg  = (float*)p; p += (size_t)N * 4;
    float* dinv = (float*)p; p += (size_t)N * 4;
    float* ew   = (float*)p; p += (size_t)E * 4;
    int*   cnt  = (int*)p;   p += (size_t)N * 4;
    int*   ptr  = (int*)p;   p += (size_t)(N + 4) * 4;
    int*   ptr2 = (int*)p;   p += (size_t)N * 4;
    int*   esrc = (int*)p;   p += (size_t)E * 4;
    int*   bsum = (int*)p;   p += (size_t)256 * 4;
    int*   boff = (int*)p;   p += (size_t)256 * 4;

    const int NB = (N + 255) / 256;            // 196 scan blocks

    // CSR build
    hipMemsetAsync(deg, 0, (size_t)N * sizeof(float), stream);
    hipMemsetAsync(cnt, 0, (size_t)N * sizeof(int), stream);
    hist_kernel<<<(E + 255) / 256, 256, 0, stream>>>(row, col, deg, cnt, E);
    dinv_kernel<<<(N + 255) / 256, 256, 0, stream>>>(deg, dinv, N);
    bsum_kernel <<<NB, 256, 0, stream>>>(cnt, bsum, N);
    bscan_kernel<<<1, 256, 0, stream>>>(bsum, boff, NB);
    cscan_kernel<<<NB, 256, 0, stream>>>(cnt, boff, ptr, ptr2, N, NB);
    scatter_kernel<<<(E + 255) / 256, 256, 0, stream>>>(row, col, dinv, ptr2, esrc, ew, E);

    // weight/x converts
    wt_kernel<<<(256 * 512 + 255) / 256, 256, 0, stream>>>(in_w, wti, 256, 512);
    for (int i = 0; i < 4; ++i)
        wt_kernel<<<(512 * 512 + 255) / 256, 256, 0, stream>>>(
            conv_w + (size_t)i * 512 * 512, wtc + (size_t)i * 512 * 512, 512, 512);
    wt_kernel<<<(512 * 256 + 255) / 256, 256, 0, stream>>>(out_w, wto, 512, 256);
    xconv_kernel<<<(MPAD * 32 + 255) / 256, 256, 0, stream>>>(x, xb, N, MPAD);

    const int mt = MPAD / 128;

    // h0 = silu(x @ in_w + in_b)
    mfma_gemm<0, 1, 1, 0><<<dim3(4, mt), 256, 0, stream>>>(
        xb, 256, wti, 256, nullptr, h0, H512, in_b, N, 256);

    short* hc = h0;
    short* hn = h1;
    for (int l = 0; l < 2; ++l) {
        // T = hc @ W1
        mfma_gemm<0, 0, 0, 0><<<dim3(4, mt), 256, 0, stream>>>(
            hc, H512, wtc + (size_t)(l * 2 + 1) * 512 * 512, 512,
            nullptr, T, H512, nullptr, N, 512);
        // U = Lhat @ T   (gather, no atomics)
        gather_kernel<<<(N + 3) / 4, 256, 0, stream>>>(ptr, esrc, ew, T, U, N);
        // hn = silu(hc @ W0 + U + b)
        mfma_gemm<1, 1, 1, 0><<<dim3(4, mt), 256, 0, stream>>>(
            hc, H512, wtc + (size_t)(l * 2 + 0) * 512 * 512, 512,
            U, hn, H512, conv_b + (size_t)l * H512, N, 512);
        short* tmp = hc; hc = hn; hn = tmp;
    }

    // out = hc @ out_w + out_b   (fp32, guarded)
    mfma_gemm<0, 1, 0, 1><<<dim3(2, mt), 256, 0, stream>>>(
        hc, H512, wto, 512, nullptr, d_out, 256, out_b, N, 512);
}